// Round 8
// baseline (102.384 us; speedup 1.0000x reference)
//
#include <hip/hip_runtime.h>
#include <stdint.h>

// ScoreAggregation: N=8192, T=4 x E=131072 edges, H=4 heads.
// out_i = mean_h [ (S_total + sum_nz (e^leaky(A_ij)-1) s_j) / (N + sum_nz (e^leaky(A_ij)-1)) ]
// A_ij[h] = c_tot*(s_i*w_src[h] + s_j*w_tgt[h]) + sum_t cnt_t*emb[h][t]
// Dedup at (i,j) required. r4-r7 lesson: phase-2 dependent scattered reads
// (~600 lines/block) are the stubborn ~40us wall. -> full counting sort:
// all scatter happens as fire-and-forget WRITES; phase 2 reads its bucket
// as ONE contiguous coalesced run.

#define NN 8192
#define TT 4
#define EE 131072
#define DD 32
#define HH 4
#define NEG_SLOPE 0.2f

#define NBK  2048        // buckets = src>>2
#define RPB  4           // rows per bucket
#define SEG  128         // LDS hash slots per row
#define SBLK 256         // sort blocks
#define EPB  2048        // edges per sort block
#define A_EPT 8
#define EMPTY 0xFFFFFFFFu

// ws byte offsets (all 256-aligned):
#define OF_F    0                          // float[32] consts
#define OF_CNT  256                        // u8 [SBLK][NBK]    512 KB
#define OF_OFFS 524544                     // u16[NBK][SBLK]    1 MB
#define OF_TOT  1573120                    // u32[NBK]          8 KB
#define OF_BASE 1581312                    // u32[NBK+1]
#define OF_PACK 1589760                    // u32[SBLK*EPB]     2 MB (val | rank<<28)
#define OF_SORT 3686912                    // u32[T*E]          2 MB (17-bit entries)
// f: f[0]=S_total, f[1..4]=w_src, f[5..8]=w_tgt, f[9+h*4+t]=emb

__global__ void __launch_bounds__(256) kS1(const int* __restrict__ ei,
                                           uint8_t* __restrict__ cnt,
                                           uint32_t* __restrict__ packed) {
    __shared__ uint32_t hist[NBK];       // 8 KB
    int tid = threadIdx.x;
    #pragma unroll
    for (int j = 0; j < NBK / 256; ++j) hist[tid + j * 256] = 0;
    __syncthreads();

    uint32_t blk = blockIdx.x;
    uint32_t gtid = blk * 256u + (uint32_t)tid;
    uint32_t t  = gtid >> 14;                            // 16384 threads/type
    uint32_t e0 = (gtid & 16383u) * A_EPT;
    const int4* sp = (const int4*)(ei + (size_t)(t * 2) * EE + e0);
    const int4* tp = (const int4*)(ei + (size_t)(t * 2 + 1) * EE + e0);

    uint32_t val[A_EPT];     // (src<<15)|(tgt<<2)|t ; bucket = val>>17
    uint32_t rnk[A_EPT];
    #pragma unroll
    for (int k = 0; k < A_EPT / 4; ++k) {
        int4 s4 = sp[k];
        int4 t4 = tp[k];
        val[k*4+0] = ((uint32_t)s4.x << 15) | ((uint32_t)t4.x << 2) | t;
        val[k*4+1] = ((uint32_t)s4.y << 15) | ((uint32_t)t4.y << 2) | t;
        val[k*4+2] = ((uint32_t)s4.z << 15) | ((uint32_t)t4.z << 2) | t;
        val[k*4+3] = ((uint32_t)s4.w << 15) | ((uint32_t)t4.w << 2) | t;
    }
    #pragma unroll
    for (int k = 0; k < A_EPT; ++k)
        rnk[k] = atomicAdd(&hist[val[k] >> 17], 1u);     // rank in (blk,bucket); max<=12 (r4 pass)
    __syncthreads();

    // cnt[blk][bucket] u8, coalesced 8 B/thread
    uint8_t* cb = cnt + (size_t)blk * NBK;
    uint32_t lo = 0, hi = 0;
    #pragma unroll
    for (int j = 0; j < 4; ++j) lo |= (hist[tid * 8 + j] & 0xffu) << (8 * j);
    #pragma unroll
    for (int j = 0; j < 4; ++j) hi |= (hist[tid * 8 + 4 + j] & 0xffu) << (8 * j);
    uint2 cpair; cpair.x = lo; cpair.y = hi;
    ((uint2*)cb)[tid] = cpair;

    // packed vals, coalesced 32 B/thread
    uint32_t* pb = packed + (size_t)blk * EPB;
    uint4 q0, q1;
    q0.x = val[0] | (rnk[0] << 28); q0.y = val[1] | (rnk[1] << 28);
    q0.z = val[2] | (rnk[2] << 28); q0.w = val[3] | (rnk[3] << 28);
    q1.x = val[4] | (rnk[4] << 28); q1.y = val[5] | (rnk[5] << 28);
    q1.z = val[6] | (rnk[6] << 28); q1.w = val[7] | (rnk[7] << 28);
    ((uint4*)pb)[tid * 2]     = q0;
    ((uint4*)pb)[tid * 2 + 1] = q1;
}

// 32 blocks; block B scans buckets [B*64, B*64+64) across all 256 sort blocks.
__global__ void __launch_bounds__(256) kS2(const uint8_t* __restrict__ cnt,
                                           uint16_t* __restrict__ offs,
                                           uint32_t* __restrict__ totals) {
    __shared__ uint8_t  ct[SBLK * 64];   // [k][b'] 16 KB
    __shared__ uint16_t of[64 * SBLK];   // [b'][k] 32 KB
    int tid = threadIdx.x;
    int B = blockIdx.x;

    uint32_t* ct32 = (uint32_t*)ct;
    #pragma unroll
    for (int j = 0; j < 16; ++j) {
        int idx = j * 256 + tid;         // [0,4096) u32s
        int k = idx >> 4, col = idx & 15;
        ct32[idx] = ((const uint32_t*)(cnt + (size_t)k * NBK + B * 64))[col];
    }
    __syncthreads();

    if (tid < 64) {
        uint32_t run = 0;
        for (int k = 0; k < SBLK; ++k) {
            of[tid * SBLK + k] = (uint16_t)run;
            run += ct[k * 64 + tid];
        }
        totals[B * 64 + tid] = run;
    }
    __syncthreads();

    uint32_t* o32 = (uint32_t*)of;
    uint32_t* d32 = (uint32_t*)(offs + (size_t)B * 64 * SBLK);
    #pragma unroll
    for (int j = 0; j < 32; ++j) d32[j * 256 + tid] = o32[j * 256 + tid];
}

// 1 block: exclusive scan of totals -> bases; plus consts + S_total.
__global__ void kS3(const uint32_t* __restrict__ totals,
                    uint32_t* __restrict__ bases,
                    const float* __restrict__ scores,
                    const float* __restrict__ ete,
                    const float* __restrict__ aw,
                    float* __restrict__ f) {
    __shared__ uint32_t wsum[256];
    int tid = threadIdx.x;
    uint32_t loc[NBK / 256];
    uint32_t ls = 0;
    #pragma unroll
    for (int j = 0; j < NBK / 256; ++j) {
        loc[j] = ls;
        ls += totals[tid * (NBK / 256) + j];
    }
    wsum[tid] = ls;
    __syncthreads();
    for (int off = 1; off < 256; off <<= 1) {
        uint32_t u = (tid >= off) ? wsum[tid - off] : 0u;
        __syncthreads();
        wsum[tid] += u;
        __syncthreads();
    }
    uint32_t base = (tid == 0) ? 0u : wsum[tid - 1];
    #pragma unroll
    for (int j = 0; j < NBK / 256; ++j)
        bases[tid * (NBK / 256) + j] = base + loc[j];
    if (tid == 255) bases[NBK] = wsum[255];

    __shared__ float red[256];
    float s = 0.f;
    for (int i = tid; i < NN; i += 256) s += scores[i];
    red[tid] = s;
    __syncthreads();
    for (int off = 128; off > 0; off >>= 1) {
        if (tid < off) red[tid] += red[tid + off];
        __syncthreads();
    }
    if (tid == 0) f[0] = red[0];
    if (tid < HH) {
        f[1 + tid] = aw[tid * (DD + 2)];            // w[0]
        f[5 + tid] = aw[tid * (DD + 2) + DD + 1];   // w[D+1]
    }
    if (tid < HH * TT) {
        int h = tid / TT, t = tid % TT;
        float acc = 0.f;
        for (int d = 0; d < DD; ++d)
            acc += ete[t * DD + d] * aw[h * (DD + 2) + 1 + d];
        f[9 + tid] = acc;
    }
}

// 256 blocks: scatter edges to bucket-major sorted array (stores only).
__global__ void __launch_bounds__(256) kS4(const uint32_t* __restrict__ packed,
                                           const uint16_t* __restrict__ offs,
                                           const uint32_t* __restrict__ bases,
                                           uint32_t* __restrict__ sorted) {
    __shared__ uint32_t lbase[NBK];      // 8 KB
    __shared__ uint16_t lofs[NBK];       // 4 KB
    int tid = threadIdx.x;
    uint32_t blk = blockIdx.x;
    #pragma unroll
    for (int j = 0; j < NBK / 256; ++j) {
        int b = j * 256 + tid;
        lbase[b] = bases[b];
        lofs[b]  = offs[(size_t)b * SBLK + blk];
    }
    __syncthreads();
    const uint4* pb = (const uint4*)(packed + (size_t)blk * EPB);
    #pragma unroll
    for (int q = 0; q < 2; ++q) {
        uint4 p = pb[tid * 2 + q];
        uint32_t w[4] = {p.x, p.y, p.z, p.w};
        #pragma unroll
        for (int c = 0; c < 4; ++c) {
            uint32_t v = w[c] & 0x0FFFFFFFu;
            uint32_t r = w[c] >> 28;
            uint32_t b = v >> 17;
            sorted[lbase[b] + lofs[b] + r] = v & 0x1FFFFu;
        }
    }
}

__global__ void __launch_bounds__(256) kB(const float* __restrict__ scores,
                                          const uint32_t* __restrict__ sorted,
                                          const uint32_t* __restrict__ bases,
                                          const float* __restrict__ f,
                                          float* __restrict__ out) {
    __shared__ uint32_t tab[RPB * SEG];  // 2 KB
    int tid = threadIdx.x;
    tab[tid] = EMPTY;
    tab[tid + 256] = EMPTY;
    uint32_t b = blockIdx.x;

    float st = f[0];
    float wsrc[HH], wtgt[HH], em[HH * TT];
    #pragma unroll
    for (int h = 0; h < HH; ++h) { wsrc[h] = f[1 + h]; wtgt[h] = f[5 + h]; }
    #pragma unroll
    for (int k = 0; k < HH * TT; ++k) em[k] = f[9 + k];
    uint32_t lo = bases[b], hi = bases[b + 1];
    __syncthreads();

    // contiguous coalesced read of this bucket's edges (mean 256)
    for (uint32_t i = lo + tid; i < hi; i += 256) {
        uint32_t v   = sorted[i];
        uint32_t row = (v >> 15) & 3u;
        uint32_t tgt = (v >> 2) & 8191u;
        uint32_t tt  = v & 3u;
        uint32_t inc = 1u << (13 + 4 * tt);
        uint32_t fresh = tgt | inc;
        uint32_t pos = (tgt * 2654435761u) >> 25;
        uint32_t hb = row * SEG;
        while (true) {
            uint32_t cur = atomicCAS(&tab[hb + pos], EMPTY, fresh);
            if (cur == EMPTY) break;
            bool done = false;
            while ((cur & 0x1FFFu) == tgt) {
                uint32_t prev = atomicCAS(&tab[hb + pos], cur, cur + inc);
                if (prev == cur) { done = true; break; }
                cur = prev;
            }
            if (done) break;
            pos = (pos + 1) & (SEG - 1);
        }
    }
    __syncthreads();

    // accumulate: 4 waves x 1 row, zero atomics
    int wave = tid >> 6, lane = tid & 63;
    int r = wave;
    float si = scores[b * RPB + r];
    float num[HH] = {0.f, 0.f, 0.f, 0.f};
    float den[HH] = {0.f, 0.f, 0.f, 0.f};
    #pragma unroll
    for (int half = 0; half < 2; ++half) {
        uint32_t w = tab[r * SEG + half * 64 + lane];
        if (w != EMPTY) {
            uint32_t tgt = w & 0x1FFFu;
            float c0 = (float)((w >> 13) & 15u);
            float c1 = (float)((w >> 17) & 15u);
            float c2 = (float)((w >> 21) & 15u);
            float c3 = (float)((w >> 25) & 15u);
            float ctot = c0 + c1 + c2 + c3;
            float sj = scores[tgt];
            #pragma unroll
            for (int h = 0; h < HH; ++h) {
                float a = ctot * (si * wsrc[h] + sj * wtgt[h])
                        + c0 * em[h * 4 + 0] + c1 * em[h * 4 + 1]
                        + c2 * em[h * 4 + 2] + c3 * em[h * 4 + 3];
                a = (a >= 0.f) ? a : NEG_SLOPE * a;
                float ex = __expf(a) - 1.f;
                den[h] += ex;
                num[h] += ex * sj;
            }
        }
    }
    #pragma unroll
    for (int m = 32; m > 0; m >>= 1) {
        #pragma unroll
        for (int h = 0; h < HH; ++h) {
            num[h] += __shfl_xor(num[h], m, 64);
            den[h] += __shfl_xor(den[h], m, 64);
        }
    }
    if (lane == 0) {
        float acc = 0.f;
        #pragma unroll
        for (int h = 0; h < HH; ++h)
            acc += (st + num[h]) / ((float)NN + den[h]);
        out[b * RPB + r] = acc * (1.f / HH);
    }
}

extern "C" void kernel_launch(void* const* d_in, const int* in_sizes, int n_in,
                              void* d_out, int out_size, void* d_ws, size_t ws_size,
                              hipStream_t stream) {
    const float* scores = (const float*)d_in[0];
    const float* ete    = (const float*)d_in[1];
    const int*   ei     = (const int*)d_in[2];
    const float* aw     = (const float*)d_in[3];
    float* out = (float*)d_out;

    char* ws = (char*)d_ws;
    float*    f      = (float*)(ws + OF_F);
    uint8_t*  cnt    = (uint8_t*)(ws + OF_CNT);
    uint16_t* offs   = (uint16_t*)(ws + OF_OFFS);
    uint32_t* totals = (uint32_t*)(ws + OF_TOT);
    uint32_t* bases  = (uint32_t*)(ws + OF_BASE);
    uint32_t* packed = (uint32_t*)(ws + OF_PACK);
    uint32_t* sorted = (uint32_t*)(ws + OF_SORT);

    kS1<<<SBLK, 256, 0, stream>>>(ei, cnt, packed);
    kS2<<<32, 256, 0, stream>>>(cnt, offs, totals);
    kS3<<<1, 256, 0, stream>>>(totals, bases, scores, ete, aw, f);
    kS4<<<SBLK, 256, 0, stream>>>(packed, offs, bases, sorted);
    kB<<<NBK, 256, 0, stream>>>(scores, sorted, bases, f, out);
}